// Round 2
// baseline (310.169 us; speedup 1.0000x reference)
//
#include <hip/hip_runtime.h>
#include <hip/hip_bf16.h>

// NTM cell forward: T=512, B=32, D=1024, N=128. All I/O f32.
// R11: R10's hoisted-split GEMM with the staging coverage bug fixed.
// R10 staged only 16 of 32 K-columns per row per kk (2 threads/row x 8
// elems) -> stale LDS -> absmax 6079. Now 4 threads/row x 8 elems x 2
// row-blocks = full coverage. k-loop is a pure bf16 reload pipeline
// (8x 16B global loads + 8x ds_write_b128 per thread per kk, zero split
// VALU). Identical 3-MFMA split math / accumulation order to R9.
// ws layout: C (41,943,040 B) | x_hi | x_lo (33,554,432 B each) |
//            w_hi | w_lo (1,310,720 B each)  => 111,673,344 B total.
// Falls back to the R9 in-kernel-split GEMM if ws_size is smaller.

typedef __attribute__((ext_vector_type(8))) short bf16x8;
typedef __attribute__((ext_vector_type(4))) float f32x4;
typedef __attribute__((ext_vector_type(2))) float f32x2;
typedef __attribute__((ext_vector_type(4))) unsigned short u16x4;
typedef __attribute__((ext_vector_type(8))) unsigned short u16x8;

static constexpr int T_STEPS = 512;
static constexpr int BATCH   = 32;
static constexpr int DDIM    = 1024;
static constexpr int NDIM    = 128;
static constexpr int LDC     = 5 * NDIM;         // 640
static constexpr int MROWS   = T_STEPS * BATCH;  // 16384
static constexpr int OUT_N   = T_STEPS * BATCH * NDIM;  // 2,097,152

static constexpr size_t C_BYTES    = (size_t)MROWS * LDC * 4;            // 41,943,040
static constexpr size_t XS_ELEMS   = (size_t)MROWS * DDIM;               // 16,777,216
static constexpr size_t WSP_ELEMS  = 5ull * NDIM * DDIM;                 // 655,360
static constexpr size_t NEED_BYTES = C_BYTES + 4 * XS_ELEMS + 4 * WSP_ELEMS;  // 111,673,344

__device__ __forceinline__ void split2(float v, unsigned short& hi, unsigned short& lo) {
    unsigned u  = __builtin_bit_cast(unsigned, v);
    unsigned uh = u & 0xFFFF0000u;
    hi = (unsigned short)(uh >> 16);
    float d = v - __builtin_bit_cast(float, uh);
    lo = (unsigned short)(__builtin_bit_cast(unsigned, d) >> 16);
}

// ---------------- Phase 0: one-shot fp32 -> bf16 hi/lo split ----------------
// Grid covers x (4,194,304 f32x4) then the 5 weights (163,840 f32x4) exactly.
__global__ __launch_bounds__(256) void split_kernel(
    const float* __restrict__ x,
    const float* __restrict__ w0, const float* __restrict__ w1,
    const float* __restrict__ w2, const float* __restrict__ w3,
    const float* __restrict__ w4,
    unsigned short* __restrict__ xhi, unsigned short* __restrict__ xlo,
    unsigned short* __restrict__ whi, unsigned short* __restrict__ wlo)
{
    const size_t idx = (size_t)blockIdx.x * 256 + threadIdx.x;
    const size_t e = idx * 4;

    const float* src;
    unsigned short* dh;
    unsigned short* dl;
    if (e < XS_ELEMS) {
        src = x + e;
        dh = xhi + e;
        dl = xlo + e;
    } else {
        const size_t wi = e - XS_ELEMS;                   // element offset in W-space
        const int n = (int)(wi >> 17);                    // 131,072 elems per weight
        const size_t off = wi & 131071;
        const float* wp = w0;
        if (n == 1) wp = w1;
        else if (n == 2) wp = w2;
        else if (n == 3) wp = w3;
        else if (n == 4) wp = w4;
        src = wp + off;
        dh = whi + wi;
        dl = wlo + wi;
    }

    f32x4 v = *(const f32x4*)src;
    u16x4 h, l;
#pragma unroll
    for (int j = 0; j < 4; ++j) {
        unsigned short hh, ll;
        split2(v[j], hh, ll);
        h[j] = hh; l[j] = ll;
    }
    *(u16x4*)dh = h;
    *(u16x4*)dl = l;
}

// ---------------- Phase 1: LDS-staged bf16 GEMM (pre-split inputs) ----------
// 1D grid 640, XCD-affine swizzle. kk-loop: stage(regs->LDS) | barrier |
// prefetch kk+1 (8x 16B bf16 loads) | ds_read + 48 MFMA | barrier.
static constexpr int LSTR = 40;
static constexpr int OAH = 0, OAL = 128 * LSTR, OBH = 2 * 128 * LSTR, OBL = 3 * 128 * LSTR;

__global__ __launch_bounds__(256, 3) void gemm2_kernel(
    const unsigned short* __restrict__ xhi, const unsigned short* __restrict__ xlo,
    const unsigned short* __restrict__ whi, const unsigned short* __restrict__ wlo,
    float* __restrict__ C)
{
    __shared__ unsigned short lds[4 * 128 * LSTR];  // 40,960 B

    const int id  = blockIdx.x;
    const int xcd = id & 7;
    const int kq  = id >> 3;        // 0..79
    const int bn  = kq % 5;
    const int bm  = (kq / 5) * 8 + xcd;

    const int tid  = threadIdx.x;
    const int wave = tid >> 6, lane = tid & 63;
    const int quad = lane >> 4, l16 = lane & 15;
    const int wm = (wave >> 1) * 64, wn = (wave & 1) * 64;
    const int m0 = bm * 128;

    f32x4 acc[4][4];
#pragma unroll
    for (int i = 0; i < 4; ++i)
#pragma unroll
        for (int j = 0; j < 4; ++j) acc[i][j] = (f32x4)(0.0f);

    // staging: 4 threads/row, 8 bf16 (16B) each, rows srow4 and srow4+64
    const int srow4 = tid >> 2;         // 0..63
    const int sc8   = (tid & 3) * 8;    // col 0/8/16/24
    const int fa = (wm + l16) * LSTR + quad * 8;
    const int fb = (wn + l16) * LSTR + quad * 8;

    // per-thread global base pointers (row fixed, col = kk*32 + sc8)
    const unsigned short* pah[2];
    const unsigned short* pal[2];
    const unsigned short* pbh[2];
    const unsigned short* pbl[2];
#pragma unroll
    for (int i = 0; i < 2; ++i) {
        const size_t xoff = (size_t)(m0 + srow4 + i * 64) * DDIM + sc8;
        const size_t woff = (size_t)bn * (NDIM * DDIM) + (size_t)(srow4 + i * 64) * DDIM + sc8;
        pah[i] = xhi + xoff;
        pal[i] = xlo + xoff;
        pbh[i] = whi + woff;
        pbl[i] = wlo + woff;
    }

    // preload kk = 0
    u16x8 rah[2], ral[2], rbh[2], rbl[2];
#pragma unroll
    for (int i = 0; i < 2; ++i) {
        rah[i] = *(const u16x8*)pah[i];
        ral[i] = *(const u16x8*)pal[i];
        rbh[i] = *(const u16x8*)pbh[i];
        rbl[i] = *(const u16x8*)pbl[i];
    }

    for (int kk = 0; kk < 32; ++kk) {
        // ---- stage: registers -> LDS (regs die here) ----
#pragma unroll
        for (int i = 0; i < 2; ++i) {
            const int o = (srow4 + i * 64) * LSTR + sc8;
            *(u16x8*)&lds[OAH + o] = rah[i];
            *(u16x8*)&lds[OAL + o] = ral[i];
            *(u16x8*)&lds[OBH + o] = rbh[i];
            *(u16x8*)&lds[OBL + o] = rbl[i];
        }
        __syncthreads();

        // ---- prefetch kk+1 into the same regs (clamped reload at end) ----
        const int kn = ((kk + 1 < 32) ? kk + 1 : 31) * 32;
#pragma unroll
        for (int i = 0; i < 2; ++i) {
            rah[i] = *(const u16x8*)(pah[i] + kn);
            ral[i] = *(const u16x8*)(pal[i] + kn);
            rbh[i] = *(const u16x8*)(pbh[i] + kn);
            rbl[i] = *(const u16x8*)(pbl[i] + kn);
        }

        // ---- compute: phased frag reads to bound register pressure ----
        bf16x8 ah[4], bh[4];
#pragma unroll
        for (int i = 0; i < 4; ++i) {
            ah[i] = *(const bf16x8*)&lds[OAH + fa + i * 16 * LSTR];
            bh[i] = *(const bf16x8*)&lds[OBH + fb + i * 16 * LSTR];
        }
#pragma unroll
        for (int mi = 0; mi < 4; ++mi)
#pragma unroll
            for (int ni = 0; ni < 4; ++ni)
                acc[mi][ni] = __builtin_amdgcn_mfma_f32_16x16x32_bf16(
                    ah[mi], bh[ni], acc[mi][ni], 0, 0, 0);
        {
            bf16x8 bl[4];
#pragma unroll
            for (int i = 0; i < 4; ++i)
                bl[i] = *(const bf16x8*)&lds[OBL + fb + i * 16 * LSTR];
#pragma unroll
            for (int mi = 0; mi < 4; ++mi)
#pragma unroll
                for (int ni = 0; ni < 4; ++ni)
                    acc[mi][ni] = __builtin_amdgcn_mfma_f32_16x16x32_bf16(
                        ah[mi], bl[ni], acc[mi][ni], 0, 0, 0);
        }
        {
            bf16x8 al[4];
#pragma unroll
            for (int i = 0; i < 4; ++i)
                al[i] = *(const bf16x8*)&lds[OAL + fa + i * 16 * LSTR];
#pragma unroll
            for (int mi = 0; mi < 4; ++mi)
#pragma unroll
                for (int ni = 0; ni < 4; ++ni)
                    acc[mi][ni] = __builtin_amdgcn_mfma_f32_16x16x32_bf16(
                        al[mi], bh[ni], acc[mi][ni], 0, 0, 0);
        }
        __syncthreads();
    }

#pragma unroll
    for (int mi = 0; mi < 4; ++mi)
#pragma unroll
        for (int ni = 0; ni < 4; ++ni) {
            const int row = m0 + wm + mi * 16 + quad * 4;
            const int col = bn * 128 + wn + ni * 16 + l16;
#pragma unroll
            for (int r = 0; r < 4; ++r)
                C[(size_t)(row + r) * LDC + col] = acc[mi][ni][r];
        }
}

// ---------------- Fallback GEMM (in-kernel split; used if ws too small) -----
__global__ __launch_bounds__(256, 3) void gemm_kernel(
    const float* __restrict__ x,
    const float* __restrict__ w0, const float* __restrict__ w1,
    const float* __restrict__ w2, const float* __restrict__ w3,
    const float* __restrict__ w4,
    float* __restrict__ C)
{
    __shared__ unsigned short lds[4 * 128 * LSTR];  // 40,960 B

    const float* Ws[5] = {w0, w1, w2, w3, w4};
    const int id  = blockIdx.x;
    const int xcd = id & 7;
    const int kq  = id >> 3;        // 0..79
    const int bn  = kq % 5;
    const int bm  = (kq / 5) * 8 + xcd;

    const int tid  = threadIdx.x;
    const int wave = tid >> 6, lane = tid & 63;
    const int quad = lane >> 4, l16 = lane & 15;
    const int wm = (wave >> 1) * 64, wn = (wave & 1) * 64;
    const int m0 = bm * 128;
    const float* wsrc = Ws[bn];

    f32x4 acc[4][4];
#pragma unroll
    for (int i = 0; i < 4; ++i)
#pragma unroll
        for (int j = 0; j < 4; ++j) acc[i][j] = (f32x4)(0.0f);

    const int srow = tid >> 3;      // 0..31
    const int sc4  = tid & 7;       // 16B chunk
    const int fa = (wm + l16) * LSTR + quad * 8;
    const int fb = (wn + l16) * LSTR + quad * 8;

    const float* xp[4];
    const float* wp[4];
#pragma unroll
    for (int i = 0; i < 4; ++i) {
        xp[i] = x    + (size_t)(m0 + srow + i * 32) * DDIM + sc4 * 4;
        wp[i] = wsrc + (size_t)(srow + i * 32) * DDIM + sc4 * 4;
    }

    f32x4 ra[4], rb[4];
#pragma unroll
    for (int i = 0; i < 4; ++i) { ra[i] = *(const f32x4*)xp[i]; rb[i] = *(const f32x4*)wp[i]; }

    for (int kk = 0; kk < 32; ++kk) {
#pragma unroll
        for (int i = 0; i < 4; ++i) {
            u16x4 ha, la, hb, lb;
#pragma unroll
            for (int j = 0; j < 4; ++j) {
                unsigned short h, l;
                split2(ra[i][j], h, l); ha[j] = h; la[j] = l;
                split2(rb[i][j], h, l); hb[j] = h; lb[j] = l;
            }
            const int o = (srow + i * 32) * LSTR + sc4 * 4;
            *(u16x4*)&lds[OAH + o] = ha;
            *(u16x4*)&lds[OAL + o] = la;
            *(u16x4*)&lds[OBH + o] = hb;
            *(u16x4*)&lds[OBL + o] = lb;
        }
        __syncthreads();

        const int kn = (kk + 1 < 32) ? kk + 1 : 31;
#pragma unroll
        for (int i = 0; i < 4; ++i) {
            ra[i] = *(const f32x4*)(xp[i] + kn * 32);
            rb[i] = *(const f32x4*)(wp[i] + kn * 32);
        }

        bf16x8 ah[4], bh[4];
#pragma unroll
        for (int i = 0; i < 4; ++i) {
            ah[i] = *(const bf16x8*)&lds[OAH + fa + i * 16 * LSTR];
            bh[i] = *(const bf16x8*)&lds[OBH + fb + i * 16 * LSTR];
        }
#pragma unroll
        for (int mi = 0; mi < 4; ++mi)
#pragma unroll
            for (int ni = 0; ni < 4; ++ni)
                acc[mi][ni] = __builtin_amdgcn_mfma_f32_16x16x32_bf16(
                    ah[mi], bh[ni], acc[mi][ni], 0, 0, 0);
        {
            bf16x8 bl[4];
#pragma unroll
            for (int i = 0; i < 4; ++i)
                bl[i] = *(const bf16x8*)&lds[OBL + fb + i * 16 * LSTR];
#pragma unroll
            for (int mi = 0; mi < 4; ++mi)
#pragma unroll
                for (int ni = 0; ni < 4; ++ni)
                    acc[mi][ni] = __builtin_amdgcn_mfma_f32_16x16x32_bf16(
                        ah[mi], bl[ni], acc[mi][ni], 0, 0, 0);
        }
        {
            bf16x8 al[4];
#pragma unroll
            for (int i = 0; i < 4; ++i)
                al[i] = *(const bf16x8*)&lds[OAL + fa + i * 16 * LSTR];
#pragma unroll
            for (int mi = 0; mi < 4; ++mi)
#pragma unroll
                for (int ni = 0; ni < 4; ++ni)
                    acc[mi][ni] = __builtin_amdgcn_mfma_f32_16x16x32_bf16(
                        al[mi], bh[ni], acc[mi][ni], 0, 0, 0);
        }
        __syncthreads();
    }

#pragma unroll
    for (int mi = 0; mi < 4; ++mi)
#pragma unroll
        for (int ni = 0; ni < 4; ++ni) {
            const int row = m0 + wm + mi * 16 + quad * 4;
            const int col = bn * 128 + wn + ni * 16 + l16;
#pragma unroll
            for (int r = 0; r < 4; ++r)
                C[(size_t)(row + r) * LDC + col] = acc[mi][ni][r];
        }
}

// ---------------- knorm prep ----------------
__global__ __launch_bounds__(256) void knorm_kernel(float* __restrict__ C)
{
    const int r    = blockIdx.x * 4 + (threadIdx.x >> 6);
    const int lane = threadIdx.x & 63;
    float* base = C + (size_t)r * LDC;

    f32x2 k2 = *(const f32x2*)(base + lane * 2);
    f32x2 v2 = *(const f32x2*)(base + NDIM + lane * 2);
    f32x2 w2 = *(const f32x2*)(base + 4 * NDIM + lane * 2);

    float ss = k2.x * k2.x + k2.y * k2.y;
#pragma unroll
    for (int off = 32; off >= 1; off >>= 1) ss += __shfl_xor(ss, off, 64);
    float inv = __builtin_amdgcn_rcpf(sqrtf(ss) + 1e-6f);

    f32x2 kn = {k2.x * inv, k2.y * inv};
    f32x2 wv = {v2.x * w2.x, v2.y * w2.y};
    *(f32x2*)(base + lane * 2) = kn;
    *(f32x2*)(base + NDIM + lane * 2) = wv;
}

// ---------------- recurrent scan ----------------
__device__ __forceinline__ float tanh_fast(float xx) {
    float ex = __builtin_amdgcn_exp2f(xx * 2.8853900817779268f);  // e^(2x)
    float r  = __builtin_amdgcn_rcpf(ex + 1.0f);
    return fmaf(-2.0f, r, 1.0f);
}

template <int CTRL, int RMASK>
__device__ __forceinline__ float dpp_add(float x) {
    int yi = __builtin_amdgcn_update_dpp(
        0, __builtin_bit_cast(int, x), CTRL, RMASK, 0xF, true);
    return x + __builtin_bit_cast(float, yi);
}

// Sum across each 32-lane group; valid in lanes 16..31 / 48..63.
__device__ __forceinline__ float dpp_reduce32(float x) {
    x = dpp_add<0xB1,  0xF>(x);  // + lane^1
    x = dpp_add<0x4E,  0xF>(x);  // + lane^2
    x = dpp_add<0x141, 0xF>(x);  // row_half_mirror: + lane^4
    x = dpp_add<0x140, 0xF>(x);  // row_mirror: + lane^8
    x = dpp_add<0x142, 0xA>(x);  // row_bcast15: rows 1,3 += row 0,2 sum
    return x;
}

// Grid 512 x 256; 32-lane group per S-row, 4 f32/lane, 2 rows/wave.
__global__ __launch_bounds__(256) void ntm_scan_kernel(
    const float* __restrict__ C, const float* __restrict__ S0,
    float* __restrict__ out)
{
    const int L    = blockIdx.x;            // 0..511
    const int b    = (L & 7) + 8 * ((L >> 3) & 3);
    const int row  = (L >> 5) * 8 + (threadIdx.x >> 5);
    const int g    = threadIdx.x & 31;
    const int col0 = g * 4;

    f32x4 S = *(const f32x4*)(S0 + ((size_t)b * NDIM + row) * NDIM + col0);

    const size_t STRIDE = (size_t)BATCH * LDC;
    const float* pb = C + (size_t)b * LDC;

    f32x4 kS[4], qS[4];
    float eS[4], wvS[4];

#pragma unroll
    for (int s = 0; s < 2; ++s) {
        const float* p = pb + (size_t)s * STRIDE;
        kS[s]  = *(const f32x4*)(p + col0);
        qS[s]  = *(const f32x4*)(p + 2 * NDIM + col0);
        eS[s]  = p[3 * NDIM + row];
        wvS[s] = p[NDIM + row];
    }

    float* op = out + (size_t)b * NDIM + row;

    for (int ti = 0; ti < T_STEPS / 4; ++ti) {
#pragma unroll
        for (int j = 0; j < 4; ++j) {
            const int t = ti * 4 + j;
            {
                int tp = t + 2;
                if (tp > T_STEPS - 1) tp = T_STEPS - 1;
                const float* p = pb + (size_t)tp * STRIDE;
                const int ps = (j + 2) & 3;
                kS[ps]  = *(const f32x4*)(p + col0);
                qS[ps]  = *(const f32x4*)(p + 2 * NDIM + col0);
                eS[ps]  = p[3 * NDIM + row];
                wvS[ps] = p[NDIM + row];
            }
            float dot = 0.0f;
#pragma unroll
            for (int u = 0; u < 4; ++u) {
                float t0  = fmaf(-eS[j], S[u], wvS[j]);
                float pre = fmaf(kS[j][u], t0, S[u]);
                S[u] = tanh_fast(pre);
                dot = fmaf(S[u], qS[j][u], dot);
            }
            dot = dpp_reduce32(dot);

            if ((threadIdx.x & 31) == 31)
                op[(size_t)t * BATCH * NDIM] = dot;  // raw; silu in epilogue
        }
    }

    *(f32x4*)(out + (size_t)T_STEPS * BATCH * NDIM
              + ((size_t)b * NDIM + row) * NDIM + col0) = S;
}

// ---------------- silu epilogue: y = d^2 * sigmoid(d) over out[0:OUT_N] ----
__global__ __launch_bounds__(256) void silu_kernel(float* __restrict__ out)
{
    const int i = blockIdx.x * 256 + threadIdx.x;  // f32x4 index
    f32x4 d = ((const f32x4*)out)[i];
    f32x4 y;
#pragma unroll
    for (int j = 0; j < 4; ++j) {
        float sg = __builtin_amdgcn_rcpf(
            1.0f + __builtin_amdgcn_exp2f(-d[j] * 1.4426950408889634f));
        y[j] = d[j] * d[j] * sg;
    }
    ((f32x4*)out)[i] = y;
}

extern "C" void kernel_launch(void* const* d_in, const int* in_sizes, int n_in,
                              void* d_out, int out_size, void* d_ws, size_t ws_size,
                              hipStream_t stream) {
    const float* x  = (const float*)d_in[0];
    const float* S0 = (const float*)d_in[1];
    const float* wk = (const float*)d_in[2];
    const float* wv = (const float*)d_in[3];
    const float* wq = (const float*)d_in[4];
    const float* we = (const float*)d_in[5];
    const float* ww = (const float*)d_in[6];
    float* out = (float*)d_out;
    float* C   = (float*)d_ws;

    if (ws_size >= NEED_BYTES) {
        unsigned short* xhi = (unsigned short*)((char*)d_ws + C_BYTES);
        unsigned short* xlo = xhi + XS_ELEMS;
        unsigned short* whi = xlo + XS_ELEMS;
        unsigned short* wlo = whi + WSP_ELEMS;
        const int nblk = (int)((XS_ELEMS / 4 + WSP_ELEMS / 4) / 256);  // 17,024
        split_kernel<<<nblk, 256, 0, stream>>>(x, wk, wv, wq, we, ww, xhi, xlo, whi, wlo);
        gemm2_kernel<<<640, 256, 0, stream>>>(xhi, xlo, whi, wlo, C);
    } else {
        gemm_kernel<<<640, 256, 0, stream>>>(x, wk, wv, wq, we, ww, C);
    }
    knorm_kernel<<<MROWS / 4, 256, 0, stream>>>(C);
    ntm_scan_kernel<<<512, 256, 0, stream>>>(C, S0, out);
    silu_kernel<<<OUT_N / 1024, 256, 0, stream>>>(out);
}

// Round 3
// 276.304 us; speedup vs baseline: 1.1226x; 1.1226x over previous
//
#include <hip/hip_runtime.h>
#include <hip/hip_bf16.h>

// NTM cell forward: T=512, B=32, D=1024, N=128. All I/O f32.
// R12: single-bf16 GEMM. R11 proved staging VALU is free (hoisting the
// split was a null) -> the 3-product split-bf16 emulation is pure waste
// given the bf16-calibrated absmax threshold (28.32, measured 4.0 at
// near-fp32). Now: in-kernel RNE f32->bf16 convert, 2 LDS buffers
// (20,480 B), 16 MFMA/kk (was 48). No split pass. ws needs only C.
// Scan: prefetch depth 2 -> 4 (slots[8], static indices) to cover L3
// latency at the grid-limited 2 waves/SIMD occupancy.

typedef __attribute__((ext_vector_type(8))) short bf16x8;
typedef __attribute__((ext_vector_type(4))) float f32x4;
typedef __attribute__((ext_vector_type(2))) float f32x2;
typedef __attribute__((ext_vector_type(4))) unsigned short u16x4;

static constexpr int T_STEPS = 512;
static constexpr int BATCH   = 32;
static constexpr int DDIM    = 1024;
static constexpr int NDIM    = 128;
static constexpr int LDC     = 5 * NDIM;         // 640
static constexpr int MROWS   = T_STEPS * BATCH;  // 16384
static constexpr int OUT_N   = T_STEPS * BATCH * NDIM;  // 2,097,152

// round-to-nearest-even f32 -> bf16
__device__ __forceinline__ unsigned short rne_bf16(float v) {
    unsigned u = __builtin_bit_cast(unsigned, v);
    u += 0x7FFFu + ((u >> 16) & 1u);
    return (unsigned short)(u >> 16);
}

// ---------------- Phase 1: LDS-staged single-bf16 GEMM ----------------
// 1D grid 640, XCD-affine swizzle. kk-loop: convert+stage -> barrier ->
// prefetch kk+1 (8x f32x4 global loads) -> 8x ds_read_b128 + 16 MFMA ->
// barrier. Stage regs die at the convert; vmcnt wait for the prefetch
// lands at the NEXT convert, covered by this iteration's MFMA phase.
static constexpr int LSTR = 40;
static constexpr int OA = 0, OB = 128 * LSTR;

__global__ __launch_bounds__(256, 3) void gemm3_kernel(
    const float* __restrict__ x,
    const float* __restrict__ w0, const float* __restrict__ w1,
    const float* __restrict__ w2, const float* __restrict__ w3,
    const float* __restrict__ w4,
    float* __restrict__ C)
{
    __shared__ unsigned short lds[2 * 128 * LSTR];  // 20,480 B

    const float* Ws[5] = {w0, w1, w2, w3, w4};
    const int id  = blockIdx.x;
    const int xcd = id & 7;
    const int kq  = id >> 3;        // 0..79
    const int bn  = kq % 5;
    const int bm  = (kq / 5) * 8 + xcd;

    const int tid  = threadIdx.x;
    const int wave = tid >> 6, lane = tid & 63;
    const int quad = lane >> 4, l16 = lane & 15;
    const int wm = (wave >> 1) * 64, wn = (wave & 1) * 64;
    const int m0 = bm * 128;
    const float* wsrc = Ws[bn];

    f32x4 acc[4][4];
#pragma unroll
    for (int i = 0; i < 4; ++i)
#pragma unroll
        for (int j = 0; j < 4; ++j) acc[i][j] = (f32x4)(0.0f);

    const int srow = tid >> 3;      // 0..31
    const int sc4  = tid & 7;       // 16B chunk (4 floats)
    const int fa = (wm + l16) * LSTR + quad * 8;
    const int fb = (wn + l16) * LSTR + quad * 8;

    const float* xp[4];
    const float* wp[4];
#pragma unroll
    for (int i = 0; i < 4; ++i) {
        xp[i] = x    + (size_t)(m0 + srow + i * 32) * DDIM + sc4 * 4;
        wp[i] = wsrc + (size_t)(srow + i * 32) * DDIM + sc4 * 4;
    }

    // preload kk = 0
    f32x4 ra[4], rb[4];
#pragma unroll
    for (int i = 0; i < 4; ++i) { ra[i] = *(const f32x4*)xp[i]; rb[i] = *(const f32x4*)wp[i]; }

    for (int kk = 0; kk < 32; ++kk) {
        // ---- stage: RNE convert current regs -> LDS (regs die here) ----
#pragma unroll
        for (int i = 0; i < 4; ++i) {
            u16x4 ha, hb;
#pragma unroll
            for (int j = 0; j < 4; ++j) {
                ha[j] = rne_bf16(ra[i][j]);
                hb[j] = rne_bf16(rb[i][j]);
            }
            const int o = (srow + i * 32) * LSTR + sc4 * 4;
            *(u16x4*)&lds[OA + o] = ha;
            *(u16x4*)&lds[OB + o] = hb;
        }
        __syncthreads();

        // ---- prefetch kk+1 into the same regs (clamped reload at end) ----
        const int kn = (kk + 1 < 32) ? kk + 1 : 31;
#pragma unroll
        for (int i = 0; i < 4; ++i) {
            ra[i] = *(const f32x4*)(xp[i] + kn * 32);
            rb[i] = *(const f32x4*)(wp[i] + kn * 32);
        }

        // ---- compute: 8x ds_read_b128 + 16 MFMA ----
        bf16x8 ah[4], bh[4];
#pragma unroll
        for (int i = 0; i < 4; ++i) {
            ah[i] = *(const bf16x8*)&lds[OA + fa + i * 16 * LSTR];
            bh[i] = *(const bf16x8*)&lds[OB + fb + i * 16 * LSTR];
        }
#pragma unroll
        for (int mi = 0; mi < 4; ++mi)
#pragma unroll
            for (int ni = 0; ni < 4; ++ni)
                acc[mi][ni] = __builtin_amdgcn_mfma_f32_16x16x32_bf16(
                    ah[mi], bh[ni], acc[mi][ni], 0, 0, 0);
        __syncthreads();
    }

#pragma unroll
    for (int mi = 0; mi < 4; ++mi)
#pragma unroll
        for (int ni = 0; ni < 4; ++ni) {
            const int row = m0 + wm + mi * 16 + quad * 4;
            const int col = bn * 128 + wn + ni * 16 + l16;
#pragma unroll
            for (int r = 0; r < 4; ++r)
                C[(size_t)(row + r) * LDC + col] = acc[mi][ni][r];
        }
}

// ---------------- knorm prep ----------------
__global__ __launch_bounds__(256) void knorm_kernel(float* __restrict__ C)
{
    const int r    = blockIdx.x * 4 + (threadIdx.x >> 6);
    const int lane = threadIdx.x & 63;
    float* base = C + (size_t)r * LDC;

    f32x2 k2 = *(const f32x2*)(base + lane * 2);
    f32x2 v2 = *(const f32x2*)(base + NDIM + lane * 2);
    f32x2 w2 = *(const f32x2*)(base + 4 * NDIM + lane * 2);

    float ss = k2.x * k2.x + k2.y * k2.y;
#pragma unroll
    for (int off = 32; off >= 1; off >>= 1) ss += __shfl_xor(ss, off, 64);
    float inv = __builtin_amdgcn_rcpf(sqrtf(ss) + 1e-6f);

    f32x2 kn = {k2.x * inv, k2.y * inv};
    f32x2 wv = {v2.x * w2.x, v2.y * w2.y};
    *(f32x2*)(base + lane * 2) = kn;
    *(f32x2*)(base + NDIM + lane * 2) = wv;
}

// ---------------- recurrent scan ----------------
__device__ __forceinline__ float tanh_fast(float xx) {
    float ex = __builtin_amdgcn_exp2f(xx * 2.8853900817779268f);  // e^(2x)
    float r  = __builtin_amdgcn_rcpf(ex + 1.0f);
    return fmaf(-2.0f, r, 1.0f);
}

template <int CTRL, int RMASK>
__device__ __forceinline__ float dpp_add(float x) {
    int yi = __builtin_amdgcn_update_dpp(
        0, __builtin_bit_cast(int, x), CTRL, RMASK, 0xF, true);
    return x + __builtin_bit_cast(float, yi);
}

// Sum across each 32-lane group; valid in lanes 16..31 / 48..63.
__device__ __forceinline__ float dpp_reduce32(float x) {
    x = dpp_add<0xB1,  0xF>(x);  // + lane^1
    x = dpp_add<0x4E,  0xF>(x);  // + lane^2
    x = dpp_add<0x141, 0xF>(x);  // row_half_mirror: + lane^4
    x = dpp_add<0x140, 0xF>(x);  // row_mirror: + lane^8
    x = dpp_add<0x142, 0xA>(x);  // row_bcast15: rows 1,3 += row 0,2 sum
    return x;
}

// Grid 512 x 256; 32-lane group per S-row, 4 f32/lane, 2 rows/wave.
// XCD-affine batches; unroll-8 rotation-free depth-4 prefetch; raw-dot store.
__global__ __launch_bounds__(256) void ntm_scan_kernel(
    const float* __restrict__ C, const float* __restrict__ S0,
    float* __restrict__ out)
{
    const int L    = blockIdx.x;            // 0..511
    const int b    = (L & 7) + 8 * ((L >> 3) & 3);
    const int row  = (L >> 5) * 8 + (threadIdx.x >> 5);
    const int g    = threadIdx.x & 31;
    const int col0 = g * 4;

    f32x4 S = *(const f32x4*)(S0 + ((size_t)b * NDIM + row) * NDIM + col0);

    const size_t STRIDE = (size_t)BATCH * LDC;
    const float* pb = C + (size_t)b * LDC;

    f32x4 kS[8], qS[8];
    float eS[8], wvS[8];

#pragma unroll
    for (int s = 0; s < 4; ++s) {
        const float* p = pb + (size_t)s * STRIDE;
        kS[s]  = *(const f32x4*)(p + col0);
        qS[s]  = *(const f32x4*)(p + 2 * NDIM + col0);
        eS[s]  = p[3 * NDIM + row];
        wvS[s] = p[NDIM + row];
    }

    float* op = out + (size_t)b * NDIM + row;

    for (int ti = 0; ti < T_STEPS / 8; ++ti) {
#pragma unroll
        for (int j = 0; j < 8; ++j) {
            const int t = ti * 8 + j;
            {
                int tp = t + 4;
                if (tp > T_STEPS - 1) tp = T_STEPS - 1;
                const float* p = pb + (size_t)tp * STRIDE;
                const int ps = (j + 4) & 7;
                kS[ps]  = *(const f32x4*)(p + col0);
                qS[ps]  = *(const f32x4*)(p + 2 * NDIM + col0);
                eS[ps]  = p[3 * NDIM + row];
                wvS[ps] = p[NDIM + row];
            }
            float dot = 0.0f;
#pragma unroll
            for (int u = 0; u < 4; ++u) {
                float t0  = fmaf(-eS[j], S[u], wvS[j]);
                float pre = fmaf(kS[j][u], t0, S[u]);
                S[u] = tanh_fast(pre);
                dot = fmaf(S[u], qS[j][u], dot);
            }
            dot = dpp_reduce32(dot);

            if ((threadIdx.x & 31) == 31)
                op[(size_t)t * BATCH * NDIM] = dot;  // raw; silu in epilogue
        }
    }

    *(f32x4*)(out + (size_t)T_STEPS * BATCH * NDIM
              + ((size_t)b * NDIM + row) * NDIM + col0) = S;
}

// ---------------- silu epilogue: y = d^2 * sigmoid(d) over out[0:OUT_N] ----
__global__ __launch_bounds__(256) void silu_kernel(float* __restrict__ out)
{
    const int i = blockIdx.x * 256 + threadIdx.x;  // f32x4 index
    f32x4 d = ((const f32x4*)out)[i];
    f32x4 y;
#pragma unroll
    for (int j = 0; j < 4; ++j) {
        float sg = __builtin_amdgcn_rcpf(
            1.0f + __builtin_amdgcn_exp2f(-d[j] * 1.4426950408889634f));
        y[j] = d[j] * d[j] * sg;
    }
    ((f32x4*)out)[i] = y;
}

extern "C" void kernel_launch(void* const* d_in, const int* in_sizes, int n_in,
                              void* d_out, int out_size, void* d_ws, size_t ws_size,
                              hipStream_t stream) {
    const float* x  = (const float*)d_in[0];
    const float* S0 = (const float*)d_in[1];
    const float* wk = (const float*)d_in[2];
    const float* wv = (const float*)d_in[3];
    const float* wq = (const float*)d_in[4];
    const float* we = (const float*)d_in[5];
    const float* ww = (const float*)d_in[6];
    float* out = (float*)d_out;
    float* C   = (float*)d_ws;  // 41,943,040 B

    gemm3_kernel<<<640, 256, 0, stream>>>(x, wk, wv, wq, we, ww, C);
    knorm_kernel<<<MROWS / 4, 256, 0, stream>>>(C);
    ntm_scan_kernel<<<512, 256, 0, stream>>>(C, S0, out);
    silu_kernel<<<OUT_N / 1024, 256, 0, stream>>>(out);
}

// Round 4
// 266.545 us; speedup vs baseline: 1.1637x; 1.0366x over previous
//
#include <hip/hip_runtime.h>
#include <hip/hip_bf16.h>

// NTM cell forward: T=512, B=32, D=1024, N=128. All I/O f32.
// R13: barrier-free A-resident GEMM. R12 showed the GEMM is structure-
// bound (~130us for 21.5 GFLOP): 2-barrier-per-kk loop + 5x redundant x
// traffic. Now: wconv pre-converts W to frag-swizzled bf16 (1.3 MB);
// gemm4 (256 blocks x 512 thr) stages its 64x1024 A-strip once into
// 128 KiB XOR-swizzled LDS, then runs a sync-free K-loop: per kk,
// 4 ds_read_b128 A-frags shared across 5 bn, B streamed from L2,
// 20 MFMA. x fetched once (67 MB, was 335). Scan reverted to depth-2
// (depth-4 was null) with silu folded into the lane-31 store.
// ws: C (41,943,040 B) + W2 bf16 (1,310,720 B).

typedef __attribute__((ext_vector_type(8))) short bf16x8;
typedef __attribute__((ext_vector_type(4))) float f32x4;
typedef __attribute__((ext_vector_type(2))) float f32x2;
typedef __attribute__((ext_vector_type(4))) unsigned short u16x4;
typedef __attribute__((ext_vector_type(8))) unsigned short u16x8;

static constexpr int T_STEPS = 512;
static constexpr int BATCH   = 32;
static constexpr int DDIM    = 1024;
static constexpr int NDIM    = 128;
static constexpr int LDC     = 5 * NDIM;         // 640
static constexpr int MROWS   = T_STEPS * BATCH;  // 16384
static constexpr int OUT_N   = T_STEPS * BATCH * NDIM;  // 2,097,152

static constexpr size_t C_BYTES = (size_t)MROWS * LDC * 4;  // 41,943,040

// round-to-nearest-even f32 -> bf16
__device__ __forceinline__ unsigned short rne_bf16(float v) {
    unsigned u = __builtin_bit_cast(unsigned, v);
    u += 0x7FFFu + ((u >> 16) & 1u);
    return (unsigned short)(u >> 16);
}

// ---------------- Phase 0: W f32 -> frag-swizzled bf16 ----------------
// W2 elem offset for (bn, n, k): (((bn*32 + kk)*128 + n)*4 + quad)*8 + (k&7)
// with kk = k>>5, quad = (k>>3)&3.  A wave's b-frag read (fixed bn,kk;
// n = wave*16 + l16; all quads) is then 1 KiB fully contiguous.
__global__ __launch_bounds__(256) void wconv_kernel(
    const float* __restrict__ w0, const float* __restrict__ w1,
    const float* __restrict__ w2, const float* __restrict__ w3,
    const float* __restrict__ w4,
    unsigned short* __restrict__ W2)
{
    const int idx = blockIdx.x * 256 + threadIdx.x;   // f32x4 index, 163840 total
    const size_t e = (size_t)idx * 4;
    const int bn = (int)(e >> 17);                    // 131,072 elems per weight
    const int r  = (int)(e & 131071);
    const int n  = r >> 10;
    const int k  = r & 1023;

    const float* wp = w0;
    if (bn == 1) wp = w1;
    else if (bn == 2) wp = w2;
    else if (bn == 3) wp = w3;
    else if (bn == 4) wp = w4;

    f32x4 v = *(const f32x4*)(wp + r);
    u16x4 h;
#pragma unroll
    for (int j = 0; j < 4; ++j) h[j] = rne_bf16(v[j]);

    const int kk   = k >> 5;
    const int quad = (k >> 3) & 3;
    const size_t off = ((((size_t)(bn * 32 + kk) * 128 + n) * 4 + quad) * 8) + (k & 7);
    *(u16x4*)(W2 + off) = h;
}

// ---------------- Phase 1: A-resident sync-free GEMM ----------------
// 256 blocks, 512 threads (8 waves). Block bm: rows m0..m0+63.
// Stage: 64x1024 x-strip f32 -> bf16 into 128 KiB LDS, rows XOR-swizzled
// (byte ^= (row&7)<<4 within the row's 2048 B). One barrier. Then
// kk-loop (BK=32, 32 steps, double-buffered frags, no syncs):
//   4 ds_read_b128 A-frags (shared by all bn) + 5 coalesced 16B B-loads
//   + 20 MFMA. Epilogue: 80 scalar C stores per lane.
__global__ __launch_bounds__(512, 2) void gemm4_kernel(
    const float* __restrict__ x,
    const unsigned short* __restrict__ W2,
    float* __restrict__ C)
{
    __shared__ unsigned short lds[64 * 1024];  // 131,072 B

    const int m0   = blockIdx.x * 64;
    const int tid  = threadIdx.x;
    const int wave = tid >> 6, lane = tid & 63;
    const int quad = lane >> 4, l16 = lane & 15;

    // ---- stage: coalesced 32 B/thread/iter, swizzled 16 B LDS writes ----
    {
        const int k8 = tid & 127;       // 8-elem k-group 0..127
        const int rb = tid >> 7;        // 0..3
#pragma unroll 4
        for (int it = 0; it < 16; ++it) {
            const int row = it * 4 + rb;
            const float* src = x + (size_t)(m0 + row) * DDIM + k8 * 8;
            f32x4 v0 = *(const f32x4*)src;
            f32x4 v1 = *(const f32x4*)(src + 4);
            u16x8 h;
            h[0] = rne_bf16(v0[0]); h[1] = rne_bf16(v0[1]);
            h[2] = rne_bf16(v0[2]); h[3] = rne_bf16(v0[3]);
            h[4] = rne_bf16(v1[0]); h[5] = rne_bf16(v1[1]);
            h[6] = rne_bf16(v1[2]); h[7] = rne_bf16(v1[3]);
            const int byteo = row * 2048 + ((k8 * 16) ^ ((row & 7) << 4));
            *(u16x8*)((char*)lds + byteo) = h;
        }
    }
    __syncthreads();

    f32x4 acc[5][4];
#pragma unroll
    for (int bn = 0; bn < 5; ++bn)
#pragma unroll
        for (int mi = 0; mi < 4; ++mi) acc[bn][mi] = (f32x4)(0.0f);

    const int aswz = (l16 & 7) << 4;
    // b-frag base: lane-fixed part of the swizzled W2 offset
    const unsigned short* bp = W2 + ((size_t)((wave * 16 + l16) * 4 + quad)) * 8;

    auto LDA = [&](int mi, int kk) -> bf16x8 {
        const int byteo = (mi * 16 + l16) * 2048 + ((kk * 64 + quad * 16) ^ aswz);
        return *(const bf16x8*)((const char*)lds + byteo);
    };

    bf16x8 aC[4], bC[5], aN[4], bN[5];
#pragma unroll
    for (int mi = 0; mi < 4; ++mi) aC[mi] = LDA(mi, 0);
#pragma unroll
    for (int bn = 0; bn < 5; ++bn)
        bC[bn] = *(const bf16x8*)(bp + (size_t)bn * 131072);

    for (int kk = 0; kk < 32; kk += 2) {
        // prefetch kk+1
#pragma unroll
        for (int mi = 0; mi < 4; ++mi) aN[mi] = LDA(mi, kk + 1);
#pragma unroll
        for (int bn = 0; bn < 5; ++bn)
            bN[bn] = *(const bf16x8*)(bp + (size_t)bn * 131072 + (size_t)(kk + 1) * 4096);
        // compute kk
#pragma unroll
        for (int bn = 0; bn < 5; ++bn)
#pragma unroll
            for (int mi = 0; mi < 4; ++mi)
                acc[bn][mi] = __builtin_amdgcn_mfma_f32_16x16x32_bf16(
                    aC[mi], bC[bn], acc[bn][mi], 0, 0, 0);
        // prefetch kk+2
        if (kk < 30) {
#pragma unroll
            for (int mi = 0; mi < 4; ++mi) aC[mi] = LDA(mi, kk + 2);
#pragma unroll
            for (int bn = 0; bn < 5; ++bn)
                bC[bn] = *(const bf16x8*)(bp + (size_t)bn * 131072 + (size_t)(kk + 2) * 4096);
        }
        // compute kk+1
#pragma unroll
        for (int bn = 0; bn < 5; ++bn)
#pragma unroll
            for (int mi = 0; mi < 4; ++mi)
                acc[bn][mi] = __builtin_amdgcn_mfma_f32_16x16x32_bf16(
                    aN[mi], bN[bn], acc[bn][mi], 0, 0, 0);
    }

    // ---- epilogue ----
#pragma unroll
    for (int bn = 0; bn < 5; ++bn)
#pragma unroll
        for (int mi = 0; mi < 4; ++mi) {
            const int rw = m0 + mi * 16 + quad * 4;
            const int cl = bn * 128 + wave * 16 + l16;
#pragma unroll
            for (int r = 0; r < 4; ++r)
                C[(size_t)(rw + r) * LDC + cl] = acc[bn][mi][r];
        }
}

// ---------------- knorm prep ----------------
__global__ __launch_bounds__(256) void knorm_kernel(float* __restrict__ C)
{
    const int r    = blockIdx.x * 4 + (threadIdx.x >> 6);
    const int lane = threadIdx.x & 63;
    float* base = C + (size_t)r * LDC;

    f32x2 k2 = *(const f32x2*)(base + lane * 2);
    f32x2 v2 = *(const f32x2*)(base + NDIM + lane * 2);
    f32x2 w2 = *(const f32x2*)(base + 4 * NDIM + lane * 2);

    float ss = k2.x * k2.x + k2.y * k2.y;
#pragma unroll
    for (int off = 32; off >= 1; off >>= 1) ss += __shfl_xor(ss, off, 64);
    float inv = __builtin_amdgcn_rcpf(sqrtf(ss) + 1e-6f);

    f32x2 kn = {k2.x * inv, k2.y * inv};
    f32x2 wv = {v2.x * w2.x, v2.y * w2.y};
    *(f32x2*)(base + lane * 2) = kn;
    *(f32x2*)(base + NDIM + lane * 2) = wv;
}

// ---------------- recurrent scan ----------------
__device__ __forceinline__ float tanh_fast(float xx) {
    float ex = __builtin_amdgcn_exp2f(xx * 2.8853900817779268f);  // e^(2x)
    float r  = __builtin_amdgcn_rcpf(ex + 1.0f);
    return fmaf(-2.0f, r, 1.0f);
}

template <int CTRL, int RMASK>
__device__ __forceinline__ float dpp_add(float x) {
    int yi = __builtin_amdgcn_update_dpp(
        0, __builtin_bit_cast(int, x), CTRL, RMASK, 0xF, true);
    return x + __builtin_bit_cast(float, yi);
}

// Sum across each 32-lane group; valid in lanes 16..31 / 48..63.
__device__ __forceinline__ float dpp_reduce32(float x) {
    x = dpp_add<0xB1,  0xF>(x);  // + lane^1
    x = dpp_add<0x4E,  0xF>(x);  // + lane^2
    x = dpp_add<0x141, 0xF>(x);  // row_half_mirror: + lane^4
    x = dpp_add<0x140, 0xF>(x);  // row_mirror: + lane^8
    x = dpp_add<0x142, 0xA>(x);  // row_bcast15: rows 1,3 += row 0,2 sum
    return x;
}

// Grid 512 x 256; 32-lane group per S-row, 4 f32/lane, 2 rows/wave.
// XCD-affine batches; unroll-4 rotation-free depth-2 prefetch; fused silu.
__global__ __launch_bounds__(256) void ntm_scan_kernel(
    const float* __restrict__ C, const float* __restrict__ S0,
    float* __restrict__ out)
{
    const int L    = blockIdx.x;            // 0..511
    const int b    = (L & 7) + 8 * ((L >> 3) & 3);
    const int row  = (L >> 5) * 8 + (threadIdx.x >> 5);
    const int g    = threadIdx.x & 31;
    const int col0 = g * 4;

    f32x4 S = *(const f32x4*)(S0 + ((size_t)b * NDIM + row) * NDIM + col0);

    const size_t STRIDE = (size_t)BATCH * LDC;
    const float* pb = C + (size_t)b * LDC;

    f32x4 kS[4], qS[4];
    float eS[4], wvS[4];

#pragma unroll
    for (int s = 0; s < 2; ++s) {
        const float* p = pb + (size_t)s * STRIDE;
        kS[s]  = *(const f32x4*)(p + col0);
        qS[s]  = *(const f32x4*)(p + 2 * NDIM + col0);
        eS[s]  = p[3 * NDIM + row];
        wvS[s] = p[NDIM + row];
    }

    float* op = out + (size_t)b * NDIM + row;

    for (int ti = 0; ti < T_STEPS / 4; ++ti) {
#pragma unroll
        for (int j = 0; j < 4; ++j) {
            const int t = ti * 4 + j;
            {
                int tp = t + 2;
                if (tp > T_STEPS - 1) tp = T_STEPS - 1;
                const float* p = pb + (size_t)tp * STRIDE;
                const int ps = (j + 2) & 3;
                kS[ps]  = *(const f32x4*)(p + col0);
                qS[ps]  = *(const f32x4*)(p + 2 * NDIM + col0);
                eS[ps]  = p[3 * NDIM + row];
                wvS[ps] = p[NDIM + row];
            }
            float dot = 0.0f;
#pragma unroll
            for (int u = 0; u < 4; ++u) {
                float t0  = fmaf(-eS[j], S[u], wvS[j]);
                float pre = fmaf(kS[j][u], t0, S[u]);
                S[u] = tanh_fast(pre);
                dot = fmaf(S[u], qS[j][u], dot);
            }
            dot = dpp_reduce32(dot);

            if ((threadIdx.x & 31) == 31) {
                const float d = dot;
                const float sg = __builtin_amdgcn_rcpf(
                    1.0f + __builtin_amdgcn_exp2f(-d * 1.4426950408889634f));
                op[(size_t)t * BATCH * NDIM] = d * d * sg;  // silu fused
            }
        }
    }

    *(f32x4*)(out + (size_t)T_STEPS * BATCH * NDIM
              + ((size_t)b * NDIM + row) * NDIM + col0) = S;
}

extern "C" void kernel_launch(void* const* d_in, const int* in_sizes, int n_in,
                              void* d_out, int out_size, void* d_ws, size_t ws_size,
                              hipStream_t stream) {
    const float* x  = (const float*)d_in[0];
    const float* S0 = (const float*)d_in[1];
    const float* wk = (const float*)d_in[2];
    const float* wv = (const float*)d_in[3];
    const float* wq = (const float*)d_in[4];
    const float* we = (const float*)d_in[5];
    const float* ww = (const float*)d_in[6];
    float* out = (float*)d_out;
    float* C   = (float*)d_ws;
    unsigned short* W2 = (unsigned short*)((char*)d_ws + C_BYTES);

    wconv_kernel<<<640, 256, 0, stream>>>(wk, wv, wq, we, ww, W2);
    gemm4_kernel<<<256, 512, 0, stream>>>(x, W2, C);
    knorm_kernel<<<MROWS / 4, 256, 0, stream>>>(C);
    ntm_scan_kernel<<<512, 256, 0, stream>>>(C, S0, out);
}

// Round 5
// 261.499 us; speedup vs baseline: 1.1861x; 1.0193x over previous
//
#include <hip/hip_runtime.h>
#include <hip/hip_bf16.h>

// NTM cell forward: T=512, B=32, D=1024, N=128. All I/O f32.
// R14: attack scratch/register pressure in both hot kernels.
//  - scan: VGPR_Count=28 cannot hold the 60-reg live set -> slot arrays
//    were in scratch. __launch_bounds__(256,2) (occupancy is grid-capped
//    at 2 waves/SIMD anyway) + clamp-free prefetch cursor (peeled
//    epilogue) + silu UNfused (R13 fusion cost 12us of masked trans).
//  - gemm5: R13's gemm4 (~114us vs ~25 roofline) held ~190+ live VGPRs
//    (acc 80 + 18 dbuf frags). Now 3 bn-passes ({0,1},{2,3},{4}) over the
//    same LDS-resident A-strip: live set ~100 VGPR, spill-proof; LDS
//    re-read cost bounded (~10us/CU worst case). Same stage + W2 layout
//    as R13 (verified correct).
// ws: C (41,943,040 B) + W2 bf16 (1,310,720 B).

typedef __attribute__((ext_vector_type(8))) short bf16x8;
typedef __attribute__((ext_vector_type(4))) float f32x4;
typedef __attribute__((ext_vector_type(2))) float f32x2;
typedef __attribute__((ext_vector_type(4))) unsigned short u16x4;
typedef __attribute__((ext_vector_type(8))) unsigned short u16x8;

static constexpr int T_STEPS = 512;
static constexpr int BATCH   = 32;
static constexpr int DDIM    = 1024;
static constexpr int NDIM    = 128;
static constexpr int LDC     = 5 * NDIM;         // 640
static constexpr int MROWS   = T_STEPS * BATCH;  // 16384
static constexpr int OUT_N   = T_STEPS * BATCH * NDIM;  // 2,097,152

static constexpr size_t C_BYTES = (size_t)MROWS * LDC * 4;  // 41,943,040

// round-to-nearest-even f32 -> bf16
__device__ __forceinline__ unsigned short rne_bf16(float v) {
    unsigned u = __builtin_bit_cast(unsigned, v);
    u += 0x7FFFu + ((u >> 16) & 1u);
    return (unsigned short)(u >> 16);
}

// ---------------- Phase 0: W f32 -> frag-swizzled bf16 ----------------
// W2 elem offset for (bn, n, k): (((bn*32 + kk)*128 + n)*4 + quad)*8 + (k&7)
// with kk = k>>5, quad = (k>>3)&3. A wave's b-frag read (fixed bn,kk) is
// 1 KiB fully contiguous.
__global__ __launch_bounds__(256) void wconv_kernel(
    const float* __restrict__ w0, const float* __restrict__ w1,
    const float* __restrict__ w2, const float* __restrict__ w3,
    const float* __restrict__ w4,
    unsigned short* __restrict__ W2)
{
    const int idx = blockIdx.x * 256 + threadIdx.x;   // f32x4 index, 163840 total
    const size_t e = (size_t)idx * 4;
    const int bn = (int)(e >> 17);                    // 131,072 elems per weight
    const int r  = (int)(e & 131071);
    const int n  = r >> 10;
    const int k  = r & 1023;

    const float* wp = w0;
    if (bn == 1) wp = w1;
    else if (bn == 2) wp = w2;
    else if (bn == 3) wp = w3;
    else if (bn == 4) wp = w4;

    f32x4 v = *(const f32x4*)(wp + r);
    u16x4 h;
#pragma unroll
    for (int j = 0; j < 4; ++j) h[j] = rne_bf16(v[j]);

    const int kk   = k >> 5;
    const int quad = (k >> 3) & 3;
    const size_t off = ((((size_t)(bn * 32 + kk) * 128 + n) * 4 + quad) * 8) + (k & 7);
    *(u16x4*)(W2 + off) = h;
}

// ---------------- Phase 1: A-resident GEMM, bn-pass structure ----------------
template<int BN0, int NB>
__device__ __forceinline__ void gemm_pass(
    const unsigned short (&lds)[64 * 1024],
    const unsigned short* __restrict__ bp,
    float* __restrict__ C,
    int m0, int wave, int quad, int l16, int aswz)
{
    auto LDA = [&](int mi, int kk) -> bf16x8 {
        const int byteo = (mi * 16 + l16) * 2048 + ((kk * 64 + quad * 16) ^ aswz);
        return *(const bf16x8*)((const char*)lds + byteo);
    };

    f32x4 acc[NB][4];
#pragma unroll
    for (int q = 0; q < NB; ++q)
#pragma unroll
        for (int mi = 0; mi < 4; ++mi) acc[q][mi] = (f32x4)(0.0f);

    const unsigned short* bpp[NB];
#pragma unroll
    for (int q = 0; q < NB; ++q) bpp[q] = bp + (size_t)(BN0 + q) * 131072;

    bf16x8 aC[4], bC[NB], aN[4], bN[NB];
#pragma unroll
    for (int mi = 0; mi < 4; ++mi) aC[mi] = LDA(mi, 0);
#pragma unroll
    for (int q = 0; q < NB; ++q) bC[q] = *(const bf16x8*)bpp[q];

    for (int kk = 0; kk < 32; kk += 2) {
        // prefetch kk+1
#pragma unroll
        for (int mi = 0; mi < 4; ++mi) aN[mi] = LDA(mi, kk + 1);
#pragma unroll
        for (int q = 0; q < NB; ++q)
            bN[q] = *(const bf16x8*)(bpp[q] + (size_t)(kk + 1) * 4096);
        // compute kk
#pragma unroll
        for (int q = 0; q < NB; ++q)
#pragma unroll
            for (int mi = 0; mi < 4; ++mi)
                acc[q][mi] = __builtin_amdgcn_mfma_f32_16x16x32_bf16(
                    aC[mi], bC[q], acc[q][mi], 0, 0, 0);
        // prefetch kk+2
        if (kk < 30) {
#pragma unroll
            for (int mi = 0; mi < 4; ++mi) aC[mi] = LDA(mi, kk + 2);
#pragma unroll
            for (int q = 0; q < NB; ++q)
                bC[q] = *(const bf16x8*)(bpp[q] + (size_t)(kk + 2) * 4096);
        }
        // compute kk+1
#pragma unroll
        for (int q = 0; q < NB; ++q)
#pragma unroll
            for (int mi = 0; mi < 4; ++mi)
                acc[q][mi] = __builtin_amdgcn_mfma_f32_16x16x32_bf16(
                    aN[mi], bN[q], acc[q][mi], 0, 0, 0);
    }

    // per-pass epilogue (overlaps next pass's loads)
#pragma unroll
    for (int q = 0; q < NB; ++q)
#pragma unroll
        for (int mi = 0; mi < 4; ++mi) {
            const int rw = m0 + mi * 16 + quad * 4;
            const int cl = (BN0 + q) * 128 + wave * 16 + l16;
#pragma unroll
            for (int r = 0; r < 4; ++r)
                C[(size_t)(rw + r) * LDC + cl] = acc[q][mi][r];
        }
}

// 256 blocks, 512 threads (8 waves), 1 block/CU (128 KiB LDS). Stage the
// 64x1024 A-strip once (XOR-swizzled rows), one barrier, then 3 bn-passes.
__global__ __launch_bounds__(512, 2) void gemm5_kernel(
    const float* __restrict__ x,
    const unsigned short* __restrict__ W2,
    float* __restrict__ C)
{
    __shared__ unsigned short lds[64 * 1024];  // 131,072 B

    const int m0   = blockIdx.x * 64;
    const int tid  = threadIdx.x;
    const int wave = tid >> 6, lane = tid & 63;
    const int quad = lane >> 4, l16 = lane & 15;

    // ---- stage: coalesced 32 B/thread/iter, swizzled 16 B LDS writes ----
    {
        const int k8 = tid & 127;       // 8-elem k-group 0..127
        const int rb = tid >> 7;        // 0..3
#pragma unroll 4
        for (int it = 0; it < 16; ++it) {
            const int row = it * 4 + rb;
            const float* src = x + (size_t)(m0 + row) * DDIM + k8 * 8;
            f32x4 v0 = *(const f32x4*)src;
            f32x4 v1 = *(const f32x4*)(src + 4);
            u16x8 h;
            h[0] = rne_bf16(v0[0]); h[1] = rne_bf16(v0[1]);
            h[2] = rne_bf16(v0[2]); h[3] = rne_bf16(v0[3]);
            h[4] = rne_bf16(v1[0]); h[5] = rne_bf16(v1[1]);
            h[6] = rne_bf16(v1[2]); h[7] = rne_bf16(v1[3]);
            const int byteo = row * 2048 + ((k8 * 16) ^ ((row & 7) << 4));
            *(u16x8*)((char*)lds + byteo) = h;
        }
    }
    __syncthreads();

    const int aswz = (l16 & 7) << 4;
    const unsigned short* bp = W2 + ((size_t)((wave * 16 + l16) * 4 + quad)) * 8;

    gemm_pass<0, 2>(lds, bp, C, m0, wave, quad, l16, aswz);
    gemm_pass<2, 2>(lds, bp, C, m0, wave, quad, l16, aswz);
    gemm_pass<4, 1>(lds, bp, C, m0, wave, quad, l16, aswz);
}

// ---------------- knorm prep ----------------
__global__ __launch_bounds__(256) void knorm_kernel(float* __restrict__ C)
{
    const int r    = blockIdx.x * 4 + (threadIdx.x >> 6);
    const int lane = threadIdx.x & 63;
    float* base = C + (size_t)r * LDC;

    f32x2 k2 = *(const f32x2*)(base + lane * 2);
    f32x2 v2 = *(const f32x2*)(base + NDIM + lane * 2);
    f32x2 w2 = *(const f32x2*)(base + 4 * NDIM + lane * 2);

    float ss = k2.x * k2.x + k2.y * k2.y;
#pragma unroll
    for (int off = 32; off >= 1; off >>= 1) ss += __shfl_xor(ss, off, 64);
    float inv = __builtin_amdgcn_rcpf(sqrtf(ss) + 1e-6f);

    f32x2 kn = {k2.x * inv, k2.y * inv};
    f32x2 wv = {v2.x * w2.x, v2.y * w2.y};
    *(f32x2*)(base + lane * 2) = kn;
    *(f32x2*)(base + NDIM + lane * 2) = wv;
}

// ---------------- recurrent scan ----------------
__device__ __forceinline__ float tanh_fast(float xx) {
    float ex = __builtin_amdgcn_exp2f(xx * 2.8853900817779268f);  // e^(2x)
    float r  = __builtin_amdgcn_rcpf(ex + 1.0f);
    return fmaf(-2.0f, r, 1.0f);
}

template <int CTRL, int RMASK>
__device__ __forceinline__ float dpp_add(float x) {
    int yi = __builtin_amdgcn_update_dpp(
        0, __builtin_bit_cast(int, x), CTRL, RMASK, 0xF, true);
    return x + __builtin_bit_cast(float, yi);
}

// Sum across each 32-lane group; valid in lanes 16..31 / 48..63.
__device__ __forceinline__ float dpp_reduce32(float x) {
    x = dpp_add<0xB1,  0xF>(x);  // + lane^1
    x = dpp_add<0x4E,  0xF>(x);  // + lane^2
    x = dpp_add<0x141, 0xF>(x);  // row_half_mirror: + lane^4
    x = dpp_add<0x140, 0xF>(x);  // row_mirror: + lane^8
    x = dpp_add<0x142, 0xA>(x);  // row_bcast15: rows 1,3 += row 0,2 sum
    return x;
}

// Grid 512 x 256; 32-lane group per S-row, 4 f32/lane, 2 rows/wave.
// launch_bounds(256,2): occupancy is grid-capped at 2 waves/SIMD -> give
// the register allocator the full 256-VGPR budget so slot arrays stay in
// registers (VGPR_Count was 28 -> scratch). Clamp-free prefetch cursor in
// the main loop; peeled final iteration carries the clamp.
__global__ __launch_bounds__(256, 2) void ntm_scan_kernel(
    const float* __restrict__ C, const float* __restrict__ S0,
    float* __restrict__ out)
{
    const int L    = blockIdx.x;            // 0..511
    const int b    = (L & 7) + 8 * ((L >> 3) & 3);
    const int row  = (L >> 5) * 8 + (threadIdx.x >> 5);
    const int g    = threadIdx.x & 31;
    const int col0 = g * 4;

    f32x4 S = *(const f32x4*)(S0 + ((size_t)b * NDIM + row) * NDIM + col0);

    const size_t STRIDE = (size_t)BATCH * LDC;
    const float* pb = C + (size_t)b * LDC;

    f32x4 kS[4], qS[4];
    float eS[4], wvS[4];

#pragma unroll
    for (int s = 0; s < 2; ++s) {
        const float* p = pb + (size_t)s * STRIDE;
        kS[s]  = *(const f32x4*)(p + col0);
        qS[s]  = *(const f32x4*)(p + 2 * NDIM + col0);
        eS[s]  = p[3 * NDIM + row];
        wvS[s] = p[NDIM + row];
    }

    float* opc = out + (size_t)b * NDIM + row;   // store cursor
    const float* pc = pb + 2 * STRIDE;           // prefetch cursor (t+2)

    for (int ti = 0; ti < 127; ++ti) {
#pragma unroll
        for (int j = 0; j < 4; ++j) {
            const int ps = (j + 2) & 3;
            kS[ps]  = *(const f32x4*)(pc + col0);
            qS[ps]  = *(const f32x4*)(pc + 2 * NDIM + col0);
            eS[ps]  = pc[3 * NDIM + row];
            wvS[ps] = pc[NDIM + row];
            pc += STRIDE;

            float dot = 0.0f;
#pragma unroll
            for (int u = 0; u < 4; ++u) {
                float t0  = fmaf(-eS[j], S[u], wvS[j]);
                float pre = fmaf(kS[j][u], t0, S[u]);
                S[u] = tanh_fast(pre);
                dot = fmaf(S[u], qS[j][u], dot);
            }
            dot = dpp_reduce32(dot);

            if ((threadIdx.x & 31) == 31)
                *opc = dot;  // raw; silu in epilogue
            opc += BATCH * NDIM;
        }
    }

    // peeled final outer iteration: t = 508..511, prefetch clamped
#pragma unroll
    for (int j = 0; j < 4; ++j) {
        const int ps = (j + 2) & 3;
        int tp = 510 + j;
        if (tp > T_STEPS - 1) tp = T_STEPS - 1;
        const float* p = pb + (size_t)tp * STRIDE;
        kS[ps]  = *(const f32x4*)(p + col0);
        qS[ps]  = *(const f32x4*)(p + 2 * NDIM + col0);
        eS[ps]  = p[3 * NDIM + row];
        wvS[ps] = p[NDIM + row];

        float dot = 0.0f;
#pragma unroll
        for (int u = 0; u < 4; ++u) {
            float t0  = fmaf(-eS[j], S[u], wvS[j]);
            float pre = fmaf(kS[j][u], t0, S[u]);
            S[u] = tanh_fast(pre);
            dot = fmaf(S[u], qS[j][u], dot);
        }
        dot = dpp_reduce32(dot);

        if ((threadIdx.x & 31) == 31)
            *opc = dot;
        opc += BATCH * NDIM;
    }

    *(f32x4*)(out + (size_t)T_STEPS * BATCH * NDIM
              + ((size_t)b * NDIM + row) * NDIM + col0) = S;
}

// ---------------- silu epilogue: y = d^2 * sigmoid(d) over out[0:OUT_N] ----
__global__ __launch_bounds__(256) void silu_kernel(float* __restrict__ out)
{
    const int i = blockIdx.x * 256 + threadIdx.x;  // f32x4 index
    f32x4 d = ((const f32x4*)out)[i];
    f32x4 y;
#pragma unroll
    for (int j = 0; j < 4; ++j) {
        float sg = __builtin_amdgcn_rcpf(
            1.0f + __builtin_amdgcn_exp2f(-d[j] * 1.4426950408889634f));
        y[j] = d[j] * d[j] * sg;
    }
    ((f32x4*)out)[i] = y;
}

extern "C" void kernel_launch(void* const* d_in, const int* in_sizes, int n_in,
                              void* d_out, int out_size, void* d_ws, size_t ws_size,
                              hipStream_t stream) {
    const float* x  = (const float*)d_in[0];
    const float* S0 = (const float*)d_in[1];
    const float* wk = (const float*)d_in[2];
    const float* wv = (const float*)d_in[3];
    const float* wq = (const float*)d_in[4];
    const float* we = (const float*)d_in[5];
    const float* ww = (const float*)d_in[6];
    float* out = (float*)d_out;
    float* C   = (float*)d_ws;
    unsigned short* W2 = (unsigned short*)((char*)d_ws + C_BYTES);

    wconv_kernel<<<640, 256, 0, stream>>>(wk, wv, wq, we, ww, W2);
    gemm5_kernel<<<256, 512, 0, stream>>>(x, W2, C);
    knorm_kernel<<<MROWS / 4, 256, 0, stream>>>(C);
    ntm_scan_kernel<<<512, 256, 0, stream>>>(C, S0, out);
    silu_kernel<<<OUT_N / 1024, 256, 0, stream>>>(out);
}